// Round 1
// baseline (104.115 us; speedup 1.0000x reference)
//
#include <hip/hip_runtime.h>
#include <hip/hip_bf16.h>

// Problem constants (from reference setup_inputs): B=64, IN=OUT=1024, E=8, H=8.
//
// y[b,o] = sum_e c[b,e] * (x[b,:] . weight[e,o,:])
//   c[b,e] = sum_f att[b,f] * align_conv[f,e]
//   att[b,:] = softmax(relu(tanh(mean(x[b,:]) * W_ih + b_ih + b_hh)) @ W_att^T + b_att)
//
// Kernel A: Z_e = X * W_e^T via bf16 MFMA (16x16x32), K split KC ways into ws.
// Kernel B: per-b coefficient chain + combine.

typedef short bf16x8 __attribute__((ext_vector_type(8)));   // 8 bf16 in 4 VGPRs
typedef float f32x4 __attribute__((ext_vector_type(4)));

__device__ __forceinline__ unsigned short f2bf(float f) {
    // round-to-nearest-even fp32 -> bf16
    unsigned int u = __builtin_bit_cast(unsigned int, f);
    u += 0x7fffu + ((u >> 16) & 1u);
    return (unsigned short)(u >> 16);
}

#define LDR 40  // LDS row stride in bf16 units (32 data + 8 pad -> ~2-way banks, 16B-aligned rows)

__global__ __launch_bounds__(256) void zgemm_kernel(
    const float* __restrict__ x,      // [64,1024]
    const float* __restrict__ w,      // [8,1024,1024]
    float* __restrict__ z,            // [KC,8,64,1024] partial Z
    int KC) {
    __shared__ __align__(16) unsigned short xs[64 * LDR];
    __shared__ __align__(16) unsigned short wsld[64 * LDR];

    const int bid = blockIdx.x;
    const int kc  = bid >> 7;        // grid = 128*KC
    const int r   = bid & 127;
    const int e   = r >> 4;          // 0..7
    const int ot  = r & 15;          // 0..15
    const int o0  = ot * 64;

    const int t    = threadIdx.x;
    const int lane = t & 63;
    const int wid  = t >> 6;         // wave id 0..3 -> m-strip
    const int quad = lane >> 4;      // 0..3
    const int lr   = lane & 15;      // 0..15

    const int kspan = 1024 / KC;
    const int kbase = kc * kspan;
    const int nch   = kspan >> 5;    // chunks of 32

    f32x4 acc[4];
#pragma unroll
    for (int i = 0; i < 4; ++i) acc[i] = (f32x4){0.f, 0.f, 0.f, 0.f};

    const float4* x4 = (const float4*)x;
    const float4* w4 = (const float4*)w;

    for (int ch = 0; ch < nch; ++ch) {
        const int k0 = kbase + ch * 32;
        // ---- stage 64x32 tiles of x and w[e], fp32 -> bf16, into LDS ----
#pragma unroll
        for (int it = 0; it < 2; ++it) {
            int f   = t + it * 256;       // 0..511
            int row = f >> 3;             // 0..63
            int c4  = f & 7;              // float4 within 32-float chunk
            float4 wv = w4[(e * 1024 + o0 + row) * 256 + (k0 >> 2) + c4];
            ushort4 pw;
            pw.x = f2bf(wv.x); pw.y = f2bf(wv.y); pw.z = f2bf(wv.z); pw.w = f2bf(wv.w);
            *(ushort4*)&wsld[row * LDR + c4 * 4] = pw;
            float4 xv = x4[row * 256 + (k0 >> 2) + c4];
            ushort4 px;
            px.x = f2bf(xv.x); px.y = f2bf(xv.y); px.z = f2bf(xv.z); px.w = f2bf(xv.w);
            *(ushort4*)&xs[row * LDR + c4 * 4] = px;
        }
        __syncthreads();
        // ---- MFMA: A[m=lane&15][k=quad*8+j], B[n=lane&15][k=quad*8+j] ----
        bf16x8 a = *(const bf16x8*)&xs[(wid * 16 + lr) * LDR + quad * 8];
#pragma unroll
        for (int nt = 0; nt < 4; ++nt) {
            bf16x8 bb = *(const bf16x8*)&wsld[(nt * 16 + lr) * LDR + quad * 8];
            acc[nt] = __builtin_amdgcn_mfma_f32_16x16x32_bf16(a, bb, acc[nt], 0, 0, 0);
        }
        __syncthreads();
    }

    // ---- write partial Z: C/D layout col=lane&15, row=quad*4+reg ----
    float* zb = z + ((size_t)(kc * 8 + e)) * 64 * 1024;
#pragma unroll
    for (int nt = 0; nt < 4; ++nt) {
        int o = o0 + nt * 16 + lr;
#pragma unroll
        for (int rr = 0; rr < 4; ++rr) {
            int b = wid * 16 + quad * 4 + rr;
            zb[b * 1024 + o] = acc[nt][rr];
        }
    }
}

__global__ __launch_bounds__(256) void combine_kernel(
    const float* __restrict__ x,          // [64,1024]
    const float* __restrict__ align_conv, // [8,8]
    const float* __restrict__ W_ih,       // [8,1]
    const float* __restrict__ b_ih,       // [8]
    const float* __restrict__ b_hh,       // [8]
    const float* __restrict__ W_att,      // [8,8]
    const float* __restrict__ b_att,      // [8]
    const float* __restrict__ z,          // [KC,8,64,1024]
    float* __restrict__ y,                // [64,1024]
    int KC) {
    __shared__ float red[4];
    __shared__ float csh[8];

    const int bid = blockIdx.x;           // 256 blocks: (b, o-quarter)
    const int b   = bid >> 2;
    const int oq  = bid & 3;
    const int t    = threadIdx.x;
    const int lane = t & 63;
    const int wid  = t >> 6;

    // pooled = mean(x[b,:])
    const float4* x4 = (const float4*)x;
    float4 xv = x4[b * 256 + t];
    float s = xv.x + xv.y + xv.z + xv.w;
#pragma unroll
    for (int off = 32; off > 0; off >>= 1) s += __shfl_down(s, off, 64);
    if (lane == 0) red[wid] = s;
    __syncthreads();

    if (t == 0) {
        float pooled = (red[0] + red[1] + red[2] + red[3]) * (1.0f / 1024.0f);
        float rl[8];
#pragma unroll
        for (int j = 0; j < 8; ++j) {
            float h = tanhf(pooled * W_ih[j] + b_ih[j] + b_hh[j]);
            rl[j] = h > 0.f ? h : 0.f;
        }
        float lg[8];
        float mx = -1e30f;
#pragma unroll
        for (int f = 0; f < 8; ++f) {
            float a = b_att[f];
#pragma unroll
            for (int j = 0; j < 8; ++j) a += rl[j] * W_att[f * 8 + j];
            lg[f] = a;
            mx = fmaxf(mx, a);
        }
        float den = 0.f;
#pragma unroll
        for (int f = 0; f < 8; ++f) { lg[f] = __expf(lg[f] - mx); den += lg[f]; }
        float inv = 1.0f / den;
#pragma unroll
        for (int e = 0; e < 8; ++e) {
            float c = 0.f;
#pragma unroll
            for (int f = 0; f < 8; ++f) c += lg[f] * inv * align_conv[f * 8 + e];
            csh[e] = c;
        }
    }
    __syncthreads();

    const int o = oq * 256 + t;
    float acc = 0.f;
    for (int kc = 0; kc < KC; ++kc) {
#pragma unroll
        for (int e = 0; e < 8; ++e)
            acc += csh[e] * z[(((size_t)(kc * 8 + e) * 64 + b) << 10) + o];
    }
    y[(b << 10) + o] = acc;
}

extern "C" void kernel_launch(void* const* d_in, const int* in_sizes, int n_in,
                              void* d_out, int out_size, void* d_ws, size_t ws_size,
                              hipStream_t stream) {
    const float* x          = (const float*)d_in[0];
    const float* weight     = (const float*)d_in[1];
    const float* align_conv = (const float*)d_in[2];
    const float* W_ih       = (const float*)d_in[3];
    // d_in[4] = W_hh: unused (h0 == 0)
    const float* b_ih       = (const float*)d_in[5];
    const float* b_hh       = (const float*)d_in[6];
    const float* W_att      = (const float*)d_in[7];
    const float* b_att      = (const float*)d_in[8];
    float* y = (float*)d_out;
    float* z = (float*)d_ws;

    const size_t slice = (size_t)8 * 64 * 1024 * sizeof(float);  // 2 MB per k-split
    int KC = (ws_size >= 4 * slice) ? 4 : (ws_size >= 2 * slice) ? 2 : 1;

    zgemm_kernel<<<dim3(128 * KC), dim3(256), 0, stream>>>(x, weight, z, KC);
    combine_kernel<<<dim3(256), dim3(256), 0, stream>>>(x, align_conv, W_ih, b_ih,
                                                        b_hh, W_att, b_att, z, y, KC);
}

// Round 2
// 98.761 us; speedup vs baseline: 1.0542x; 1.0542x over previous
//
#include <hip/hip_runtime.h>
#include <hip/hip_bf16.h>

// B=64, IN=OUT=1024, E=8, H=8.
// y[b,o] = sum_e c[b,e] * (x[b,:] . weight[e,o,:])
// Kernel 0: c[b,e] chain (h0=0 so W_hh drops out).
// Kernel 1: grid (ot=32 o-tiles x kc=32 k-splits); per block: stage x-tile once,
//           loop e with double-buffered LDS + reg prefetch, MFMA (A=w, B=x),
//           scale by c[b,e], accumulate; write e-free partial z[kc][b][o].
// Kernel 2: y = sum_kc z.

typedef short bf16x8 __attribute__((ext_vector_type(8)));
typedef float f32x4 __attribute__((ext_vector_type(4)));

__device__ __forceinline__ unsigned short f2bf(float f) {
    unsigned int u = __builtin_bit_cast(unsigned int, f);
    u += 0x7fffu + ((u >> 16) & 1u);
    return (unsigned short)(u >> 16);
}

#define LDR 40  // LDS row stride (bf16 units): 32 data + 8 pad

__global__ __launch_bounds__(64) void coef_kernel(
    const float* __restrict__ x,          // [64,1024]
    const float* __restrict__ align_conv, // [8,8]
    const float* __restrict__ W_ih,       // [8,1]
    const float* __restrict__ b_ih,       // [8]
    const float* __restrict__ b_hh,       // [8]
    const float* __restrict__ W_att,      // [8,8]
    const float* __restrict__ b_att,      // [8]
    float* __restrict__ ct) {             // [8,64]  (e-major)
    const int b = blockIdx.x;
    const int lane = threadIdx.x;
    const float4* x4 = (const float4*)x;
    float s = 0.f;
#pragma unroll
    for (int i = 0; i < 4; ++i) {
        float4 v = x4[b * 256 + lane + i * 64];
        s += v.x + v.y + v.z + v.w;
    }
#pragma unroll
    for (int off = 32; off > 0; off >>= 1) s += __shfl_down(s, off, 64);
    if (lane == 0) {
        float pooled = s * (1.0f / 1024.0f);
        float rl[8];
#pragma unroll
        for (int j = 0; j < 8; ++j) {
            float h = tanhf(pooled * W_ih[j] + b_ih[j] + b_hh[j]);
            rl[j] = h > 0.f ? h : 0.f;
        }
        float lg[8];
        float mx = -1e30f;
#pragma unroll
        for (int f = 0; f < 8; ++f) {
            float a = b_att[f];
#pragma unroll
            for (int j = 0; j < 8; ++j) a += rl[j] * W_att[f * 8 + j];
            lg[f] = a;
            mx = fmaxf(mx, a);
        }
        float den = 0.f;
#pragma unroll
        for (int f = 0; f < 8; ++f) { lg[f] = __expf(lg[f] - mx); den += lg[f]; }
        float inv = 1.0f / den;
#pragma unroll
        for (int e = 0; e < 8; ++e) {
            float c = 0.f;
#pragma unroll
            for (int f = 0; f < 8; ++f) c += lg[f] * inv * align_conv[f * 8 + e];
            ct[e * 64 + b] = c;
        }
    }
}

__global__ __launch_bounds__(256, 4) void zgemm_kernel(
    const float* __restrict__ x,    // [64,1024]
    const float* __restrict__ w,    // [8,1024,1024]
    const float* __restrict__ ct,   // [8,64]
    float* __restrict__ z) {        // [32,64,1024]
    __shared__ __align__(16) unsigned short xs[64 * LDR];
    __shared__ __align__(16) unsigned short wl[2][32 * LDR];
    __shared__ float csh[8 * 64];

    const int bid = blockIdx.x;
    const int ot = bid & 31;        // o-tile (32 wide)
    const int kc = bid >> 5;        // k-split (32 wide)
    const int o0 = ot * 32;
    const int k0 = kc * 32;

    const int t = threadIdx.x;
    const int lane = t & 63;
    const int wid = t >> 6;         // wave -> 16-b strip
    const int quad = lane >> 4;
    const int lr = lane & 15;

    const float4* x4 = (const float4*)x;
    const float4* w4 = (const float4*)w;

    // stage x tile 64x32 (fp32 -> bf16)
#pragma unroll
    for (int it = 0; it < 2; ++it) {
        int f = t + it * 256, row = f >> 3, c4 = f & 7;
        float4 v = x4[row * 256 + (k0 >> 2) + c4];
        ushort4 p;
        p.x = f2bf(v.x); p.y = f2bf(v.y); p.z = f2bf(v.z); p.w = f2bf(v.w);
        *(ushort4*)&xs[row * LDR + c4 * 4] = p;
    }
    // c coefficients -> LDS (512 floats)
    ((float2*)csh)[t] = ((const float2*)ct)[t];
    // prefetch w[e=0] tile (32 rows x 32 cols -> 1 float4/thread)
    const int wrow = t >> 3, wc4 = t & 7;
    float4 wreg = w4[(o0 + wrow) * 256 + (k0 >> 2) + wc4];
    __syncthreads();

    // B-fragment from x: B[n=lane&15 -> b][k=quad*8+j]; fixed across e
    bf16x8 bfrag = *(const bf16x8*)&xs[(wid * 16 + lr) * LDR + quad * 8];
    const int b = wid * 16 + lr;

    f32x4 accy[2];
    accy[0] = (f32x4){0.f, 0.f, 0.f, 0.f};
    accy[1] = (f32x4){0.f, 0.f, 0.f, 0.f};
    const f32x4 zero = (f32x4){0.f, 0.f, 0.f, 0.f};

    for (int e = 0; e < 8; ++e) {
        // convert prefetched regs into LDS buffer e&1
        ushort4 p;
        p.x = f2bf(wreg.x); p.y = f2bf(wreg.y); p.z = f2bf(wreg.z); p.w = f2bf(wreg.w);
        *(ushort4*)&wl[e & 1][wrow * LDR + wc4 * 4] = p;
        __syncthreads();
        if (e < 7) wreg = w4[((e + 1) * 1024 + o0 + wrow) * 256 + (k0 >> 2) + wc4];
        float cv = csh[e * 64 + b];
#pragma unroll
        for (int mt = 0; mt < 2; ++mt) {
            // A-fragment from w: A[m=lane&15 -> o][k=quad*8+j]
            bf16x8 afrag = *(const bf16x8*)&wl[e & 1][(mt * 16 + lr) * LDR + quad * 8];
            f32x4 d = __builtin_amdgcn_mfma_f32_16x16x32_bf16(afrag, bfrag, zero, 0, 0, 0);
#pragma unroll
            for (int rr = 0; rr < 4; ++rr) accy[mt][rr] += cv * d[rr];
        }
    }

    // D layout: col=lane&15 (=b), row=quad*4+reg (=o within 16-tile) -> float4 store
#pragma unroll
    for (int mt = 0; mt < 2; ++mt) {
        float4 out;
        out.x = accy[mt][0]; out.y = accy[mt][1]; out.z = accy[mt][2]; out.w = accy[mt][3];
        *(float4*)&z[(((size_t)(kc * 64 + b)) << 10) + o0 + mt * 16 + quad * 4] = out;
    }
}

__global__ __launch_bounds__(256) void combine_kernel(
    const float* __restrict__ z,  // [32,64,1024]
    float* __restrict__ y) {      // [64,1024]
    const int bid = blockIdx.x;   // (b, o-quarter)
    const int b = bid >> 2;
    const int oq = bid & 3;
    const int o = oq * 256 + threadIdx.x;
    float acc = 0.f;
#pragma unroll
    for (int kc = 0; kc < 32; ++kc)
        acc += z[(((size_t)(kc * 64 + b)) << 10) + o];
    y[(b << 10) + o] = acc;
}

extern "C" void kernel_launch(void* const* d_in, const int* in_sizes, int n_in,
                              void* d_out, int out_size, void* d_ws, size_t ws_size,
                              hipStream_t stream) {
    const float* x          = (const float*)d_in[0];
    const float* weight     = (const float*)d_in[1];
    const float* align_conv = (const float*)d_in[2];
    const float* W_ih       = (const float*)d_in[3];
    // d_in[4] = W_hh unused (h0 == 0)
    const float* b_ih       = (const float*)d_in[5];
    const float* b_hh       = (const float*)d_in[6];
    const float* W_att      = (const float*)d_in[7];
    const float* b_att      = (const float*)d_in[8];
    float* y = (float*)d_out;

    float* ct = (float*)d_ws;                       // 8*64 floats (2 KB)
    float* z  = (float*)((char*)d_ws + 4096);       // 32*64*1024 floats (8 MB)

    coef_kernel<<<dim3(64), dim3(64), 0, stream>>>(x, align_conv, W_ih, b_ih,
                                                   b_hh, W_att, b_att, ct);
    zgemm_kernel<<<dim3(1024), dim3(256), 0, stream>>>(x, weight, ct, z);
    combine_kernel<<<dim3(256), dim3(256), 0, stream>>>(z, y);
}